// Round 9
// baseline (151.760 us; speedup 1.0000x reference)
//
#include <hip/hip_runtime.h>

#define IN_DIM 256
#define OUT_DIM 256
#define HEADS 8
#define HEAD_DIM 32
#define NEG_SLOPE 0.2f
#define LN_EPS 1e-5f
#define LOG2E 1.4426950408889634f

typedef __attribute__((ext_vector_type(8))) short bf16x8;
typedef __attribute__((ext_vector_type(4))) float f32x4;
typedef __attribute__((ext_vector_type(4))) unsigned short us4;
typedef __attribute__((ext_vector_type(8))) unsigned short us8;
typedef __attribute__((ext_vector_type(8))) _Float16 h16x8;

__device__ inline unsigned short f2b(float f) {
  unsigned u = __float_as_uint(f);
  u += 0x7FFF + ((u >> 16) & 1);   // round-to-nearest-even
  return (unsigned short)(u >> 16);
}
__device__ inline float b2f(unsigned short u) {
  return __uint_as_float(((unsigned)u) << 16);
}

// ---------------------------------------------------------------------------
// W [k][n] fp32 -> Wt [n][k] bf16; also zero counts (runs before count_kernel)
// ---------------------------------------------------------------------------
__global__ __launch_bounds__(256) void convert_wt(const float* __restrict__ W,
                                                  unsigned short* __restrict__ Wt,
                                                  int* __restrict__ counts, int M) {
  int i = blockIdx.x * 256 + threadIdx.x;   // i = k*256 + n (coalesced read)
  int k = i >> 8, n = i & 255;
  Wt[n * 256 + k] = f2b(W[i]);
  if (i < M) counts[i] = 0;
}

// ---------------------------------------------------------------------------
// GEMM: hb = bf16(x) @ W. 128x128 tile, BK=64, 4 waves, grid (2, M/128).
// Epilogue computes a_src/a_dst (attention dots) for this block's 4 heads.
// ---------------------------------------------------------------------------
#define BM 128
#define BN 128
#define BK 64

__global__ __launch_bounds__(256) void gemm_bf16(const float* __restrict__ A,
                                                 const unsigned short* __restrict__ Bt,
                                                 unsigned short* __restrict__ C,
                                                 const float* __restrict__ att_src,
                                                 const float* __restrict__ att_dst,
                                                 float* __restrict__ a_srcP,
                                                 float* __restrict__ a_dstP, int M) {
  __shared__ unsigned short As[BM][BK + 8];   // 144B row stride
  __shared__ unsigned short Bs[BN][BK + 8];

  const int t = threadIdx.x;
  const int lane = t & 63, wid = t >> 6;
  const int wm = wid >> 1, wn = wid & 1;      // 2x2 wave grid, 64x64 per wave
  const int row0 = blockIdx.y * BM;
  const int bx = blockIdx.x;                  // column half: cols [bx*128, +128)
  const int lr = lane & 15, lk = lane >> 4;

  f32x4 acc[4][4] = {};

  for (int kk = 0; kk < IN_DIM; kk += BK) {
    __syncthreads();
#pragma unroll
    for (int c = t; c < 512; c += 256) {   // A: 128 rows x 4 quarters (16 f32)
      int r = c >> 2, q = (c & 3) * 16;
      int gr = row0 + r;
      float4 f0 = make_float4(0, 0, 0, 0), f1 = f0, f2 = f0, f3 = f0;
      if (gr < M) {
        const float4* ap = (const float4*)&A[(size_t)gr * IN_DIM + kk + q];
        f0 = ap[0]; f1 = ap[1]; f2 = ap[2]; f3 = ap[3];
      }
      us8 o0, o1;
      o0[0] = f2b(f0.x); o0[1] = f2b(f0.y); o0[2] = f2b(f0.z); o0[3] = f2b(f0.w);
      o0[4] = f2b(f1.x); o0[5] = f2b(f1.y); o0[6] = f2b(f1.z); o0[7] = f2b(f1.w);
      o1[0] = f2b(f2.x); o1[1] = f2b(f2.y); o1[2] = f2b(f2.z); o1[3] = f2b(f2.w);
      o1[4] = f2b(f3.x); o1[5] = f2b(f3.y); o1[6] = f2b(f3.z); o1[7] = f2b(f3.w);
      *(us8*)&As[r][q] = o0;
      *(us8*)&As[r][q + 8] = o1;
    }
#pragma unroll
    for (int c = t; c < 1024; c += 256) {  // B: 128 rows x 8 us8-chunks
      int r = c >> 3, off = (c & 7) * 8;
      us8 v = *(const us8*)&Bt[(size_t)(bx * BN + r) * IN_DIM + kk + off];
      *(us8*)&Bs[r][off] = v;
    }
    __syncthreads();

#pragma unroll
    for (int ks = 0; ks < 2; ++ks) {
      bf16x8 af[4], bfr[4];
#pragma unroll
      for (int i = 0; i < 4; ++i)
        af[i] = *(bf16x8*)&As[wm * 64 + i * 16 + lr][ks * 32 + lk * 8];
#pragma unroll
      for (int i = 0; i < 4; ++i)
        bfr[i] = *(bf16x8*)&Bs[wn * 64 + i * 16 + lr][ks * 32 + lk * 8];
#pragma unroll
      for (int i = 0; i < 4; ++i)
#pragma unroll
        for (int j = 0; j < 4; ++j)
          acc[i][j] = __builtin_amdgcn_mfma_f32_16x16x32_bf16(af[i], bfr[j], acc[i][j], 0, 0, 0);
    }
  }

  // ---- C store ----
#pragma unroll
  for (int i = 0; i < 4; ++i) {
#pragma unroll
    for (int q = 0; q < 4; ++q) {
      int row = row0 + wm * 64 + i * 16 + lk * 4 + q;
      if (row < M) {
#pragma unroll
        for (int j = 0; j < 4; ++j) {
          int col = bx * BN + wn * 64 + j * 16 + lr;
          C[(size_t)row * OUT_DIM + col] = f2b(acc[i][j][q]);
        }
      }
    }
  }

  // ---- fused attention dots for this block's heads ----
  // local col(j) = wn*64 + j*16 + lr -> hd = bx*4 + wn*2 + (j>>1), dd = (j&1)*16 + lr
  float att_s[4], att_d[4];
#pragma unroll
  for (int j = 0; j < 4; ++j) {
    int hd = bx * 4 + wn * 2 + (j >> 1);
    int dd = (j & 1) * 16 + lr;
    att_s[j] = att_src[hd * HEAD_DIM + dd];
    att_d[j] = att_dst[hd * HEAD_DIM + dd];
  }
#pragma unroll
  for (int i = 0; i < 4; ++i) {
#pragma unroll
    for (int q = 0; q < 4; ++q) {
      float ps0 = acc[i][0][q] * att_s[0] + acc[i][1][q] * att_s[1];
      float ps1 = acc[i][2][q] * att_s[2] + acc[i][3][q] * att_s[3];
      float pd0 = acc[i][0][q] * att_d[0] + acc[i][1][q] * att_d[1];
      float pd1 = acc[i][2][q] * att_d[2] + acc[i][3][q] * att_d[3];
#pragma unroll
      for (int off = 1; off < 16; off <<= 1) {
        ps0 += __shfl_xor(ps0, off);
        ps1 += __shfl_xor(ps1, off);
        pd0 += __shfl_xor(pd0, off);
        pd1 += __shfl_xor(pd1, off);
      }
      int row = row0 + wm * 64 + i * 16 + lk * 4 + q;
      if (lr == 0 && row < M) {
        int hb0 = bx * 4 + wn * 2;
        a_srcP[row * 8 + hb0]     = ps0;
        a_srcP[row * 8 + hb0 + 1] = ps1;
        a_dstP[row * 8 + hb0]     = pd0;
        a_dstP[row * 8 + hb0 + 1] = pd1;
      }
    }
  }
}

// ---------------------------------------------------------------------------
// CSR build: count -> 3-stage decoupled scan
// ---------------------------------------------------------------------------
__global__ __launch_bounds__(256) void count_kernel(const int* __restrict__ ei,
                                                    int* __restrict__ counts, int E) {
  int e = blockIdx.x * 256 + threadIdx.x;
  if (e >= E) return;
  atomicAdd(&counts[ei[E + e]], 1);
}

__global__ __launch_bounds__(256) void block_sums(const int* __restrict__ counts,
                                                  int* __restrict__ bsum, int n) {
  int i = blockIdx.x * 256 + threadIdx.x;
  int lane = threadIdx.x & 63, wid = threadIdx.x >> 6;
  int v = (i < n) ? counts[i] : 0;
#pragma unroll
  for (int off = 1; off < 64; off <<= 1) v += __shfl_xor(v, off);
  __shared__ int ws[4];
  if (lane == 0) ws[wid] = v;
  __syncthreads();
  if (threadIdx.x == 0) bsum[blockIdx.x] = ws[0] + ws[1] + ws[2] + ws[3];
}

__global__ __launch_bounds__(128) void scan_sums(const int* __restrict__ bsum,
                                                 int* __restrict__ bofs,
                                                 int* __restrict__ row_start,
                                                 int nb, int n) {
  int t = threadIdx.x, lane = t & 63, wid = t >> 6;
  int v = (t < nb) ? bsum[t] : 0;
  int incl = v;
#pragma unroll
  for (int off = 1; off < 64; off <<= 1) {
    int o = __shfl_up(incl, off);
    if (lane >= off) incl += o;
  }
  __shared__ int ws[2];
  if (lane == 63) ws[wid] = incl;
  __syncthreads();
  if (wid == 1) incl += ws[0];
  if (t < nb) bofs[t] = incl - v;
  if (t == nb - 1) row_start[n] = incl;
}

__global__ __launch_bounds__(256) void scan_final(const int* __restrict__ counts,
                                                  const int* __restrict__ bofs,
                                                  int* __restrict__ row_start,
                                                  int* __restrict__ cursor, int n) {
  int i = blockIdx.x * 256 + threadIdx.x;
  int lane = threadIdx.x & 63, wid = threadIdx.x >> 6;
  int v = (i < n) ? counts[i] : 0;
  int incl = v;
#pragma unroll
  for (int off = 1; off < 64; off <<= 1) {
    int o = __shfl_up(incl, off);
    if (lane >= off) incl += o;
  }
  __shared__ int ws[4];
  if (lane == 63) ws[wid] = incl;
  __syncthreads();
  int wadd = 0;
#pragma unroll
  for (int j = 0; j < 4; ++j)
    if (j < wid) wadd += ws[j];
  int excl = bofs[blockIdx.x] + wadd + incl - v;
  if (i < n) { row_start[i] = excl; cursor[i] = excl; }
}

// ---------------------------------------------------------------------------
// Fused scatter + per-edge EXP WEIGHTS (logits are O(10): exp safe in fp32;
// clamp guards fp16 range). eexp[pos][h] = fp16(exp(leaky(...)))
// ---------------------------------------------------------------------------
__global__ __launch_bounds__(256) void scatter_eexp(const int* __restrict__ ei,
                                                    int* __restrict__ cursor,
                                                    int* __restrict__ col_src,
                                                    _Float16* __restrict__ eexp,
                                                    const float* __restrict__ a_src,
                                                    const float* __restrict__ a_dst, int E) {
  int e = blockIdx.x * 256 + threadIdx.x;
  if (e >= E) return;
  int s = ei[e];
  int d = ei[E + e];
  int pos = atomicAdd(&cursor[d], 1);
  col_src[pos] = s;
  const float4* as = (const float4*)&a_src[s * 8];
  const float4* ad = (const float4*)&a_dst[d * 8];
  float4 s0 = as[0], s1 = as[1], d0 = ad[0], d1 = ad[1];
  float l[8] = {s0.x + d0.x, s0.y + d0.y, s0.z + d0.z, s0.w + d0.w,
                s1.x + d1.x, s1.y + d1.y, s1.z + d1.z, s1.w + d1.w};
  h16x8 o;
#pragma unroll
  for (int j = 0; j < 8; ++j) {
    float v = l[j];
    v = (v > 0.f) ? v : NEG_SLOPE * v;
    float w = exp2f(v * LOG2E);
    o[j] = (_Float16)fminf(w, 60000.f);
  }
  *(h16x8*)&eexp[(size_t)pos * 8] = o;
}

// ---------------------------------------------------------------------------
// Fused aggregate: ONE WAVE per node, TWO 32-lane halves each take alternate
// edge blocks; lane owns 8 dims (16B hb loads). Single pass, no softmax max.
// half = lane>>5, li = lane&31 owns dims [8li, 8li+8), head = li>>2.
// ---------------------------------------------------------------------------
__global__ __launch_bounds__(256) void aggregate_kernel(const unsigned short* __restrict__ hb,
                                                        const float* __restrict__ a_src,
                                                        const float* __restrict__ a_dst,
                                                        const int* __restrict__ row_start,
                                                        const int* __restrict__ col_src,
                                                        const _Float16* __restrict__ eexp,
                                                        const float* __restrict__ bias,
                                                        const float* __restrict__ gamma,
                                                        const float* __restrict__ beta,
                                                        float* __restrict__ out, int n_nodes) {
  int node = blockIdx.x * 4 + (threadIdx.x >> 6);
  int lane = threadIdx.x & 63;
  if (node >= n_nodes) return;

  int half = lane >> 5;
  int li = lane & 31;
  int head = li >> 2;

  int beg = row_start[node];
  int end = row_start[node + 1];

  const char* hbl = (const char*)hb + (li << 4);    // + li*8 bf16 = 16B
  const char* ee = (const char*)eexp + (head << 1);

  float S = 0.f;
  float4 accA = make_float4(0.f, 0.f, 0.f, 0.f);    // dims 8li .. +4
  float4 accB = make_float4(0.f, 0.f, 0.f, 0.f);    // dims 8li+4 .. +8

  // self contribution (half 0 only; half 1's copy merges as zero)
  {
    float ls = a_src[node * 8 + head] + a_dst[node * 8 + head];
    ls = (ls > 0.f) ? ls : NEG_SLOPE * ls;
    float w = exp2f(ls * LOG2E);
    if (half == 0) {
      us8 hv = *(const us8*)(hbl + ((unsigned)node << 9));
      S = w;
      accA.x = w * b2f(hv[0]); accA.y = w * b2f(hv[1]);
      accA.z = w * b2f(hv[2]); accA.w = w * b2f(hv[3]);
      accB.x = w * b2f(hv[4]); accB.y = w * b2f(hv[5]);
      accB.z = w * b2f(hv[6]); accB.w = w * b2f(hv[7]);
    }
  }

  int e = beg;
  for (; e + 16 <= end; e += 16) {     // 8 edges per half
    int base = e + half * 8;
    int s[8];
    float wv[8];
    us8 v[8];
#pragma unroll
    for (int j = 0; j < 8; ++j) s[j] = col_src[base + j];
#pragma unroll
    for (int j = 0; j < 8; ++j)
      wv[j] = (float)(*(const _Float16*)(ee + (((unsigned)(base + j)) << 4)));
#pragma unroll
    for (int j = 0; j < 8; ++j)
      v[j] = *(const us8*)(hbl + ((unsigned)s[j] << 9));
#pragma unroll
    for (int j = 0; j < 8; ++j) {
      S += wv[j];
      accA.x += wv[j] * b2f(v[j][0]); accA.y += wv[j] * b2f(v[j][1]);
      accA.z += wv[j] * b2f(v[j][2]); accA.w += wv[j] * b2f(v[j][3]);
      accB.x += wv[j] * b2f(v[j][4]); accB.y += wv[j] * b2f(v[j][5]);
      accB.z += wv[j] * b2f(v[j][6]); accB.w += wv[j] * b2f(v[j][7]);
    }
  }
  for (; e + 8 <= end; e += 8) {       // 4 edges per half
    int base = e + half * 4;
    int s[4];
    float wv[4];
    us8 v[4];
#pragma unroll
    for (int j = 0; j < 4; ++j) s[j] = col_src[base + j];
#pragma unroll
    for (int j = 0; j < 4; ++j)
      wv[j] = (float)(*(const _Float16*)(ee + (((unsigned)(base + j)) << 4)));
#pragma unroll
    for (int j = 0; j < 4; ++j)
      v[j] = *(const us8*)(hbl + ((unsigned)s[j] << 9));
#pragma unroll
    for (int j = 0; j < 4; ++j) {
      S += wv[j];
      accA.x += wv[j] * b2f(v[j][0]); accA.y += wv[j] * b2f(v[j][1]);
      accA.z += wv[j] * b2f(v[j][2]); accA.w += wv[j] * b2f(v[j][3]);
      accB.x += wv[j] * b2f(v[j][4]); accB.y += wv[j] * b2f(v[j][5]);
      accB.z += wv[j] * b2f(v[j][6]); accB.w += wv[j] * b2f(v[j][7]);
    }
  }
  for (; e + 2 <= end; e += 2) {       // 1 edge per half
    int idx = e + half;
    int s = col_src[idx];
    float w = (float)(*(const _Float16*)(ee + (((unsigned)idx) << 4)));
    us8 hv = *(const us8*)(hbl + ((unsigned)s << 9));
    S += w;
    accA.x += w * b2f(hv[0]); accA.y += w * b2f(hv[1]);
    accA.z += w * b2f(hv[2]); accA.w += w * b2f(hv[3]);
    accB.x += w * b2f(hv[4]); accB.y += w * b2f(hv[5]);
    accB.z += w * b2f(hv[6]); accB.w += w * b2f(hv[7]);
  }
  if (e < end && half == 0) {          // odd tail edge
    int s = col_src[e];
    float w = (float)(*(const _Float16*)(ee + (((unsigned)e) << 4)));
    us8 hv = *(const us8*)(hbl + ((unsigned)s << 9));
    S += w;
    accA.x += w * b2f(hv[0]); accA.y += w * b2f(hv[1]);
    accA.z += w * b2f(hv[2]); accA.w += w * b2f(hv[3]);
    accB.x += w * b2f(hv[4]); accB.y += w * b2f(hv[5]);
    accB.z += w * b2f(hv[6]); accB.w += w * b2f(hv[7]);
  }

  // ---- merge halves (lane li <-> lane li+32 hold same dims) ----
  accA.x += __shfl_xor(accA.x, 32); accA.y += __shfl_xor(accA.y, 32);
  accA.z += __shfl_xor(accA.z, 32); accA.w += __shfl_xor(accA.w, 32);
  accB.x += __shfl_xor(accB.x, 32); accB.y += __shfl_xor(accB.y, 32);
  accB.z += __shfl_xor(accB.z, 32); accB.w += __shfl_xor(accB.w, 32);
  S += __shfl_xor(S, 32);

  float inv = 1.f / S;
  accA.x *= inv; accA.y *= inv; accA.z *= inv; accA.w *= inv;
  accB.x *= inv; accB.y *= inv; accB.z *= inv; accB.w *= inv;

  // ---- epilogue: + bias, LayerNorm, gamma/beta (8 dims/lane) ----
  const float4* bp = (const float4*)&bias[li * 8];
  float4 b0 = bp[0], b1 = bp[1];
  accA.x += b0.x; accA.y += b0.y; accA.z += b0.z; accA.w += b0.w;
  accB.x += b1.x; accB.y += b1.y; accB.z += b1.z; accB.w += b1.w;

  float s1 = accA.x + accA.y + accA.z + accA.w + accB.x + accB.y + accB.z + accB.w;
#pragma unroll
  for (int off = 1; off < 32; off <<= 1) s1 += __shfl_xor(s1, off);
  float mean = s1 * (1.f / OUT_DIM);

  float4 cA = make_float4(accA.x - mean, accA.y - mean, accA.z - mean, accA.w - mean);
  float4 cB = make_float4(accB.x - mean, accB.y - mean, accB.z - mean, accB.w - mean);
  float s2v = cA.x * cA.x + cA.y * cA.y + cA.z * cA.z + cA.w * cA.w
            + cB.x * cB.x + cB.y * cB.y + cB.z * cB.z + cB.w * cB.w;
#pragma unroll
  for (int off = 1; off < 32; off <<= 1) s2v += __shfl_xor(s2v, off);
  float rstd = rsqrtf(s2v * (1.f / OUT_DIM) + LN_EPS);

  const float4* gp = (const float4*)&gamma[li * 8];
  const float4* ep = (const float4*)&beta[li * 8];
  float4 o;
  if (half == 0) {
    float4 g = gp[0], eb = ep[0];
    o.x = cA.x * rstd * g.x + eb.x;
    o.y = cA.y * rstd * g.y + eb.y;
    o.z = cA.z * rstd * g.z + eb.z;
    o.w = cA.w * rstd * g.w + eb.w;
  } else {
    float4 g = gp[1], eb = ep[1];
    o.x = cB.x * rstd * g.x + eb.x;
    o.y = cB.y * rstd * g.y + eb.y;
    o.z = cB.z * rstd * g.z + eb.z;
    o.w = cB.w * rstd * g.w + eb.w;
  }
  *(float4*)&out[(size_t)node * OUT_DIM + li * 8 + half * 4] = o;
}

// ---------------------------------------------------------------------------
extern "C" void kernel_launch(void* const* d_in, const int* in_sizes, int n_in,
                              void* d_out, int out_size, void* d_ws, size_t ws_size,
                              hipStream_t stream) {
  const float* x       = (const float*)d_in[0];
  const int*   ei      = (const int*)d_in[1];
  const float* W       = (const float*)d_in[2];
  const float* att_src = (const float*)d_in[3];
  const float* att_dst = (const float*)d_in[4];
  const float* bias    = (const float*)d_in[5];
  const float* gamma   = (const float*)d_in[6];
  const float* beta    = (const float*)d_in[7];
  float* out = (float*)d_out;

  const int M = in_sizes[0] / IN_DIM;   // 30000
  const int E = in_sizes[1] / 2;        // 480000
  const int NB = (M + 255) / 256;       // 118

  char* w = (char*)d_ws;
  auto carve = [&](size_t bytes) {
    char* p = w;
    w += (bytes + 255) & ~(size_t)255;
    return p;
  };
  unsigned short* Wt = (unsigned short*)carve((size_t)IN_DIM * OUT_DIM * 2);
  unsigned short* hb = (unsigned short*)carve((size_t)M * OUT_DIM * 2);
  _Float16* eexp = (_Float16*)carve((size_t)E * HEADS * 2);
  float* a_srcP = (float*)carve((size_t)M * HEADS * 4);
  float* a_dstP = (float*)carve((size_t)M * HEADS * 4);
  int* row_st   = (int*)carve((size_t)(M + 1) * 4);
  int* cursor   = (int*)carve((size_t)M * 4);
  int* counts   = (int*)carve((size_t)M * 4);
  int* bsum     = (int*)carve((size_t)NB * 4);
  int* bofs     = (int*)carve((size_t)NB * 4);
  int* col_src  = (int*)carve((size_t)E * 4);

  convert_wt<<<(IN_DIM * OUT_DIM) / 256, 256, 0, stream>>>(W, Wt, counts, M);
  count_kernel<<<(E + 255) / 256, 256, 0, stream>>>(ei, counts, E);
  block_sums<<<NB, 256, 0, stream>>>(counts, bsum, M);
  scan_sums<<<1, 128, 0, stream>>>(bsum, bofs, row_st, NB, M);
  scan_final<<<NB, 256, 0, stream>>>(counts, bofs, row_st, cursor, M);

  gemm_bf16<<<dim3(2, (M + BM - 1) / BM), 256, 0, stream>>>(x, Wt, hb, att_src, att_dst,
                                                            a_srcP, a_dstP, M);

  scatter_eexp<<<(E + 255) / 256, 256, 0, stream>>>(ei, cursor, col_src, eexp,
                                                    a_srcP, a_dstP, E);

  aggregate_kernel<<<(M + 3) / 4, 256, 0, stream>>>(hb, a_srcP, a_dstP, row_st, col_src, eexp,
                                                    bias, gamma, beta, out, M);
}

// Round 11
// 125.982 us; speedup vs baseline: 1.2046x; 1.2046x over previous
//
#include <hip/hip_runtime.h>

#define IN_DIM 256
#define OUT_DIM 256
#define HEADS 8
#define HEAD_DIM 32
#define NEG_SLOPE 0.2f
#define LN_EPS 1e-5f
#define LOG2E 1.4426950408889634f

typedef __attribute__((ext_vector_type(8))) short bf16x8;
typedef __attribute__((ext_vector_type(4))) float f32x4;
typedef __attribute__((ext_vector_type(4))) unsigned short us4;
typedef __attribute__((ext_vector_type(8))) unsigned short us8;
typedef __attribute__((ext_vector_type(8))) _Float16 h16x8;

__device__ inline unsigned short f2b(float f) {
  unsigned u = __float_as_uint(f);
  u += 0x7FFF + ((u >> 16) & 1);   // round-to-nearest-even
  return (unsigned short)(u >> 16);
}
__device__ inline float b2f(unsigned short u) {
  return __uint_as_float(((unsigned)u) << 16);
}

// ---------------------------------------------------------------------------
// W [k][n] fp32 -> Wt [n][k] bf16; also zero counts (runs before count_kernel)
// ---------------------------------------------------------------------------
__global__ __launch_bounds__(256) void convert_wt(const float* __restrict__ W,
                                                  unsigned short* __restrict__ Wt,
                                                  int* __restrict__ counts, int M) {
  int i = blockIdx.x * 256 + threadIdx.x;   // i = k*256 + n (coalesced read)
  int k = i >> 8, n = i & 255;
  Wt[n * 256 + k] = f2b(W[i]);
  if (i < M) counts[i] = 0;
}

// ---------------------------------------------------------------------------
// GEMM: hb = bf16(x) @ W. 128x256 tile, BK=64, 8 waves (2x4). x read ONCE.
// Epilogue additionally computes a_src/a_dst (attention dots) per row.
// ---------------------------------------------------------------------------
#define BM 128
#define BN 256
#define BK 64

__global__ __launch_bounds__(512) void gemm_bf16(const float* __restrict__ A,
                                                 const unsigned short* __restrict__ Bt,
                                                 unsigned short* __restrict__ C,
                                                 const float* __restrict__ att_src,
                                                 const float* __restrict__ att_dst,
                                                 float* __restrict__ a_srcP,
                                                 float* __restrict__ a_dstP, int M) {
  __shared__ unsigned short As[BM][BK + 8];   // 144B row stride
  __shared__ unsigned short Bs[BN][BK + 8];

  const int t = threadIdx.x;
  const int lane = t & 63, wid = t >> 6;
  const int wm = wid >> 2, wn = wid & 3;      // 2 x 4 wave grid, 64x64 per wave
  const int row0 = blockIdx.y * BM;
  const int lr = lane & 15, lk = lane >> 4;

  f32x4 acc[4][4] = {};

  for (int kk = 0; kk < IN_DIM; kk += BK) {
    __syncthreads();
    {  // A: 128 rows x 4 quarters (16 f32 each) = 512 chunks, 1/thread
      int r = t >> 2, q = (t & 3) * 16;
      int gr = row0 + r;
      float4 f0 = make_float4(0, 0, 0, 0), f1 = f0, f2 = f0, f3 = f0;
      if (gr < M) {
        const float4* ap = (const float4*)&A[(size_t)gr * IN_DIM + kk + q];
        f0 = ap[0]; f1 = ap[1]; f2 = ap[2]; f3 = ap[3];
      }
      us8 o0, o1;
      o0[0] = f2b(f0.x); o0[1] = f2b(f0.y); o0[2] = f2b(f0.z); o0[3] = f2b(f0.w);
      o0[4] = f2b(f1.x); o0[5] = f2b(f1.y); o0[6] = f2b(f1.z); o0[7] = f2b(f1.w);
      o1[0] = f2b(f2.x); o1[1] = f2b(f2.y); o1[2] = f2b(f2.z); o1[3] = f2b(f2.w);
      o1[4] = f2b(f3.x); o1[5] = f2b(f3.y); o1[6] = f2b(f3.z); o1[7] = f2b(f3.w);
      *(us8*)&As[r][q] = o0;
      *(us8*)&As[r][q + 8] = o1;
    }
#pragma unroll
    for (int c = t; c < 2048; c += 512) {  // B: 256 rows x 8 us8-chunks
      int r = c >> 3, off = (c & 7) * 8;
      us8 v = *(const us8*)&Bt[(size_t)r * IN_DIM + kk + off];
      *(us8*)&Bs[r][off] = v;
    }
    __syncthreads();

#pragma unroll
    for (int ks = 0; ks < 2; ++ks) {
      bf16x8 af[4], bfr[4];
#pragma unroll
      for (int i = 0; i < 4; ++i)
        af[i] = *(bf16x8*)&As[wm * 64 + i * 16 + lr][ks * 32 + lk * 8];
#pragma unroll
      for (int i = 0; i < 4; ++i)
        bfr[i] = *(bf16x8*)&Bs[wn * 64 + i * 16 + lr][ks * 32 + lk * 8];
#pragma unroll
      for (int i = 0; i < 4; ++i)
#pragma unroll
        for (int j = 0; j < 4; ++j)
          acc[i][j] = __builtin_amdgcn_mfma_f32_16x16x32_bf16(af[i], bfr[j], acc[i][j], 0, 0, 0);
    }
  }

  // ---- C store ----
#pragma unroll
  for (int i = 0; i < 4; ++i) {
#pragma unroll
    for (int q = 0; q < 4; ++q) {
      int row = row0 + wm * 64 + i * 16 + lk * 4 + q;
      if (row < M) {
#pragma unroll
        for (int j = 0; j < 4; ++j) {
          int col = wn * 64 + j * 16 + lr;
          C[(size_t)row * OUT_DIM + col] = f2b(acc[i][j][q]);
        }
      }
    }
  }

  // ---- fused attention dots: a_src/a_dst per (row, head) ----
  // col(j) = wn*64 + j*16 + lr -> head hd = wn*2 + (j>>1), d = (j&1)*16 + lr
  float att_s[4], att_d[4];
#pragma unroll
  for (int j = 0; j < 4; ++j) {
    int hd = wn * 2 + (j >> 1);
    int dd = (j & 1) * 16 + lr;
    att_s[j] = att_src[hd * HEAD_DIM + dd];
    att_d[j] = att_dst[hd * HEAD_DIM + dd];
  }
#pragma unroll
  for (int i = 0; i < 4; ++i) {
#pragma unroll
    for (int q = 0; q < 4; ++q) {
      float ps0 = acc[i][0][q] * att_s[0] + acc[i][1][q] * att_s[1];
      float ps1 = acc[i][2][q] * att_s[2] + acc[i][3][q] * att_s[3];
      float pd0 = acc[i][0][q] * att_d[0] + acc[i][1][q] * att_d[1];
      float pd1 = acc[i][2][q] * att_d[2] + acc[i][3][q] * att_d[3];
#pragma unroll
      for (int off = 1; off < 16; off <<= 1) {
        ps0 += __shfl_xor(ps0, off);
        ps1 += __shfl_xor(ps1, off);
        pd0 += __shfl_xor(pd0, off);
        pd1 += __shfl_xor(pd1, off);
      }
      int row = row0 + wm * 64 + i * 16 + lk * 4 + q;
      if (lr == 0 && row < M) {
        a_srcP[row * 8 + wn * 2]     = ps0;
        a_srcP[row * 8 + wn * 2 + 1] = ps1;
        a_dstP[row * 8 + wn * 2]     = pd0;
        a_dstP[row * 8 + wn * 2 + 1] = pd1;
      }
    }
  }
}

// ---------------------------------------------------------------------------
// CSR build: count -> block_sums -> scan_final (self-sufficient: each block
// derives its own prefix from bsum; block 0 writes row_start[n])
// ---------------------------------------------------------------------------
__global__ __launch_bounds__(256) void count_kernel(const int* __restrict__ ei,
                                                    int* __restrict__ counts, int E) {
  int e = blockIdx.x * 256 + threadIdx.x;
  if (e >= E) return;
  atomicAdd(&counts[ei[E + e]], 1);
}

__global__ __launch_bounds__(256) void block_sums(const int* __restrict__ counts,
                                                  int* __restrict__ bsum, int n) {
  int i = blockIdx.x * 256 + threadIdx.x;
  int lane = threadIdx.x & 63, wid = threadIdx.x >> 6;
  int v = (i < n) ? counts[i] : 0;
#pragma unroll
  for (int off = 1; off < 64; off <<= 1) v += __shfl_xor(v, off);
  __shared__ int ws[4];
  if (lane == 0) ws[wid] = v;
  __syncthreads();
  if (threadIdx.x == 0) bsum[blockIdx.x] = ws[0] + ws[1] + ws[2] + ws[3];
}

__global__ __launch_bounds__(256) void scan_final(const int* __restrict__ counts,
                                                  const int* __restrict__ bsum,
                                                  int* __restrict__ row_start,
                                                  int* __restrict__ cursor, int n, int nb) {
  __shared__ int bofs_s, total_s;
  int t = threadIdx.x;
  int b = blockIdx.x;
  if (t < 64) {
    int pre = 0, tot = 0;
    for (int j = t; j < nb; j += 64) {
      int v = bsum[j];
      if (j < b) pre += v;
      tot += v;
    }
#pragma unroll
    for (int off = 1; off < 64; off <<= 1) {
      pre += __shfl_xor(pre, off);
      tot += __shfl_xor(tot, off);
    }
    if (t == 0) { bofs_s = pre; total_s = tot; }
  }
  __syncthreads();

  int i = b * 256 + t;
  int lane = t & 63, wid = t >> 6;
  int v = (i < n) ? counts[i] : 0;
  int incl = v;
#pragma unroll
  for (int off = 1; off < 64; off <<= 1) {
    int o = __shfl_up(incl, off);
    if (lane >= off) incl += o;
  }
  __shared__ int ws[4];
  if (lane == 63) ws[wid] = incl;
  __syncthreads();
  int wadd = 0;
#pragma unroll
  for (int j = 0; j < 4; ++j)
    if (j < wid) wadd += ws[j];
  int excl = bofs_s + wadd + incl - v;
  if (i < n) { row_start[i] = excl; cursor[i] = excl; }
  if (b == 0 && t == 0) row_start[n] = total_s;
}

// ---------------------------------------------------------------------------
// Fused scatter + per-edge EXP WEIGHTS (logits are O(10): exp safe in fp32;
// clamp guards fp16 range). eexp[pos][h] = fp16(exp(leaky(...)))
// ---------------------------------------------------------------------------
__global__ __launch_bounds__(256) void scatter_eexp(const int* __restrict__ ei,
                                                    int* __restrict__ cursor,
                                                    int* __restrict__ col_src,
                                                    _Float16* __restrict__ eexp,
                                                    const float* __restrict__ a_src,
                                                    const float* __restrict__ a_dst, int E) {
  int e = blockIdx.x * 256 + threadIdx.x;
  if (e >= E) return;
  int s = ei[e];
  int d = ei[E + e];
  int pos = atomicAdd(&cursor[d], 1);
  col_src[pos] = s;
  const float4* as = (const float4*)&a_src[s * 8];
  const float4* ad = (const float4*)&a_dst[d * 8];
  float4 s0 = as[0], s1 = as[1], d0 = ad[0], d1 = ad[1];
  float l[8] = {s0.x + d0.x, s0.y + d0.y, s0.z + d0.z, s0.w + d0.w,
                s1.x + d1.x, s1.y + d1.y, s1.z + d1.z, s1.w + d1.w};
  h16x8 o;
#pragma unroll
  for (int j = 0; j < 8; ++j) {
    float v = l[j];
    v = (v > 0.f) ? v : NEG_SLOPE * v;
    float w = exp2f(v * LOG2E);
    o[j] = (_Float16)fminf(w, 60000.f);
  }
  *(h16x8*)&eexp[(size_t)pos * 8] = o;
}

// ---------------------------------------------------------------------------
// Fused aggregate: ONE WAVE per node (4 nodes / 256-block), SINGLE PASS,
// software-pipelined: next batch's col_src/eexp prefetched into registers
// while current batch's hb gathers + FMAs run.
// lane owns dims [4*lane, 4*lane+4), head2 = lane>>3.
// ---------------------------------------------------------------------------
__global__ __launch_bounds__(256) void aggregate_kernel(const unsigned short* __restrict__ hb,
                                                        const float* __restrict__ a_src,
                                                        const float* __restrict__ a_dst,
                                                        const int* __restrict__ row_start,
                                                        const int* __restrict__ col_src,
                                                        const _Float16* __restrict__ eexp,
                                                        const float* __restrict__ bias,
                                                        const float* __restrict__ gamma,
                                                        const float* __restrict__ beta,
                                                        float* __restrict__ out, int n_nodes) {
  int node = blockIdx.x * 4 + (threadIdx.x >> 6);
  int lane = threadIdx.x & 63;
  if (node >= n_nodes) return;

  int beg = row_start[node];
  int end = row_start[node + 1];
  int head2 = lane >> 3;

  // self weight (per head2, computed in fp32)
  float ls = a_src[node * 8 + head2] + a_dst[node * 8 + head2];
  ls = (ls > 0.f) ? ls : NEG_SLOPE * ls;
  float ws = exp2f(ls * LOG2E);

  const char* hblane = (const char*)hb + (lane << 3);     // + lane*4 bf16
  const char* eb2 = (const char*)eexp + (head2 << 1);

  float S = ws;
  float4 acc;
  {
    us4 hv = *(const us4*)(hblane + ((unsigned)node << 9));
    acc.x = ws * b2f(hv[0]); acc.y = ws * b2f(hv[1]);
    acc.z = ws * b2f(hv[2]); acc.w = ws * b2f(hv[3]);
  }

  int e = beg;
  int sP[8];
  float wP[8];
  bool haveP = (e + 8 <= end);
  if (haveP) {
#pragma unroll
    for (int j = 0; j < 8; ++j) sP[j] = col_src[e + j];
#pragma unroll
    for (int j = 0; j < 8; ++j)
      wP[j] = (float)(*(const _Float16*)(eb2 + (((unsigned)(e + j)) << 4)));
  }
  while (haveP) {
    int s[8];
    float wv[8];
#pragma unroll
    for (int j = 0; j < 8; ++j) { s[j] = sP[j]; wv[j] = wP[j]; }
    int en = e + 8;
    haveP = (en + 8 <= end);
    if (haveP) {   // issue NEXT indices/weights now; they overlap the hb gathers
#pragma unroll
      for (int j = 0; j < 8; ++j) sP[j] = col_src[en + j];
#pragma unroll
      for (int j = 0; j < 8; ++j)
        wP[j] = (float)(*(const _Float16*)(eb2 + (((unsigned)(en + j)) << 4)));
    }
    us4 v[8];
#pragma unroll
    for (int j = 0; j < 8; ++j)
      v[j] = *(const us4*)(hblane + ((unsigned)s[j] << 9));
#pragma unroll
    for (int j = 0; j < 8; ++j) {
      S += wv[j];
      acc.x += wv[j] * b2f(v[j][0]);
      acc.y += wv[j] * b2f(v[j][1]);
      acc.z += wv[j] * b2f(v[j][2]);
      acc.w += wv[j] * b2f(v[j][3]);
    }
    e = en;
  }
  for (; e < end; ++e) {
    int s = col_src[e];
    float w = (float)(*(const _Float16*)(eb2 + (((unsigned)e) << 4)));
    us4 hv = *(const us4*)(hblane + ((unsigned)s << 9));
    S += w;
    acc.x += w * b2f(hv[0]); acc.y += w * b2f(hv[1]);
    acc.z += w * b2f(hv[2]); acc.w += w * b2f(hv[3]);
  }
  float inv = 1.f / S;
  acc.x *= inv; acc.y *= inv; acc.z *= inv; acc.w *= inv;

  // ---- epilogue: + bias, LayerNorm, gamma/beta ----
  float4 b4 = *(const float4*)&bias[lane * 4];
  acc.x += b4.x; acc.y += b4.y; acc.z += b4.z; acc.w += b4.w;

  float s1 = acc.x + acc.y + acc.z + acc.w;
#pragma unroll
  for (int off = 1; off < 64; off <<= 1) s1 += __shfl_xor(s1, off);
  float mean = s1 * (1.f / OUT_DIM);

  float4 c = make_float4(acc.x - mean, acc.y - mean, acc.z - mean, acc.w - mean);
  float s2v = c.x * c.x + c.y * c.y + c.z * c.z + c.w * c.w;
#pragma unroll
  for (int off = 1; off < 64; off <<= 1) s2v += __shfl_xor(s2v, off);
  float rstd = rsqrtf(s2v * (1.f / OUT_DIM) + LN_EPS);

  float4 g4 = *(const float4*)&gamma[lane * 4];
  float4 e4 = *(const float4*)&beta[lane * 4];
  float4 o;
  o.x = c.x * rstd * g4.x + e4.x;
  o.y = c.y * rstd * g4.y + e4.y;
  o.z = c.z * rstd * g4.z + e4.z;
  o.w = c.w * rstd * g4.w + e4.w;
  *(float4*)&out[(size_t)node * OUT_DIM + lane * 4] = o;
}

// ---------------------------------------------------------------------------
extern "C" void kernel_launch(void* const* d_in, const int* in_sizes, int n_in,
                              void* d_out, int out_size, void* d_ws, size_t ws_size,
                              hipStream_t stream) {
  const float* x       = (const float*)d_in[0];
  const int*   ei      = (const int*)d_in[1];
  const float* W       = (const float*)d_in[2];
  const float* att_src = (const float*)d_in[3];
  const float* att_dst = (const float*)d_in[4];
  const float* bias    = (const float*)d_in[5];
  const float* gamma   = (const float*)d_in[6];
  const float* beta    = (const float*)d_in[7];
  float* out = (float*)d_out;

  const int M = in_sizes[0] / IN_DIM;   // 30000
  const int E = in_sizes[1] / 2;        // 480000
  const int NB = (M + 255) / 256;       // 118

  char* w = (char*)d_ws;
  auto carve = [&](size_t bytes) {
    char* p = w;
    w += (bytes + 255) & ~(size_t)255;
    return p;
  };
  unsigned short* Wt = (unsigned short*)carve((size_t)IN_DIM * OUT_DIM * 2);
  unsigned short* hb = (unsigned short*)carve((size_t)M * OUT_DIM * 2);
  _Float16* eexp = (_Float16*)carve((size_t)E * HEADS * 2);
  float* a_srcP = (float*)carve((size_t)M * HEADS * 4);
  float* a_dstP = (float*)carve((size_t)M * HEADS * 4);
  int* row_st   = (int*)carve((size_t)(M + 1) * 4);
  int* cursor   = (int*)carve((size_t)M * 4);
  int* counts   = (int*)carve((size_t)M * 4);
  int* bsum     = (int*)carve((size_t)NB * 4);
  int* col_src  = (int*)carve((size_t)E * 4);

  convert_wt<<<(IN_DIM * OUT_DIM) / 256, 256, 0, stream>>>(W, Wt, counts, M);
  count_kernel<<<(E + 255) / 256, 256, 0, stream>>>(ei, counts, E);
  block_sums<<<NB, 256, 0, stream>>>(counts, bsum, M);
  scan_final<<<NB, 256, 0, stream>>>(counts, bsum, row_st, cursor, M, NB);

  gemm_bf16<<<dim3(1, (M + BM - 1) / BM), 512, 0, stream>>>(x, Wt, hb, att_src, att_dst,
                                                            a_srcP, a_dstP, M);

  scatter_eexp<<<(E + 255) / 256, 256, 0, stream>>>(ei, cursor, col_src, eexp,
                                                    a_srcP, a_dstP, E);

  aggregate_kernel<<<(M + 3) / 4, 256, 0, stream>>>(hb, a_srcP, a_dstP, row_st, col_src, eexp,
                                                    bias, gamma, beta, out, M);
}